// Round 1
// baseline (192.420 us; speedup 1.0000x reference)
//
#include <hip/hip_runtime.h>
#include <math.h>

#define HS 4096
#define IS 2048
#define NT 4
#define NR 16384   // 4*HS
#define ZD 6144    // HS+IS

__device__ __forceinline__ float wave_reduce(float v) {
#pragma unroll
    for (int off = 32; off > 0; off >>= 1) v += __shfl_xor(v, off, 64);
    return v;
}

__device__ __forceinline__ float sigf(float x) { return 1.0f / (1.0f + expf(-x)); }

// A: Gx[t][r] = bias[r] + sum_i Wx[r][i] * x[t][i]   for all t at once
__global__ __launch_bounds__(256) void gx_kernel(
    const float* __restrict__ x,       // [4][2048]
    const float* __restrict__ weight,  // [16384][6144]; x-part cols [4096,6144)
    const float* __restrict__ bias,    // [16384]
    float* __restrict__ Gx)            // [4][16384]
{
    __shared__ float xs[NT * IS];      // 32 KB
    const int tid = threadIdx.x;
    for (int i = tid; i < NT * IS; i += 256) xs[i] = x[i];
    __syncthreads();

    const int wave = tid >> 6, lane = tid & 63;
    const int r = blockIdx.x * 4 + wave;
    const float4* wrow = reinterpret_cast<const float4*>(weight + (size_t)r * ZD + HS);
    const float4* xs4 = reinterpret_cast<const float4*>(xs);

    float a0 = 0.f, a1 = 0.f, a2 = 0.f, a3 = 0.f;
#pragma unroll
    for (int it = 0; it < (IS / 4) / 64; ++it) {   // 8 iters
        const int e = it * 64 + lane;
        const float4 w = wrow[e];
        const float4 p = xs4[e];
        const float4 q = xs4[(IS / 4) + e];
        const float4 s = xs4[2 * (IS / 4) + e];
        const float4 u = xs4[3 * (IS / 4) + e];
        a0 += w.x * p.x + w.y * p.y + w.z * p.z + w.w * p.w;
        a1 += w.x * q.x + w.y * q.y + w.z * q.z + w.w * q.w;
        a2 += w.x * s.x + w.y * s.y + w.z * s.z + w.w * s.w;
        a3 += w.x * u.x + w.y * u.y + w.z * u.z + w.w * u.w;
    }
    a0 = wave_reduce(a0); a1 = wave_reduce(a1);
    a2 = wave_reduce(a2); a3 = wave_reduce(a3);
    if (lane == 0) {
        const float bb = bias[r];
        Gx[0 * NR + r] = a0 + bb;
        Gx[1 * NR + r] = a1 + bb;
        Gx[2 * NR + r] = a2 + bb;
        Gx[3 * NR + r] = a3 + bb;
    }
}

// B: t=0 gates (h0=0, c0=0 => c = tanh(gc)*sig(gi))
__global__ __launch_bounds__(256) void step0_kernel(
    const float* __restrict__ Gx,      // [4][16384], use t=0 slice
    float* __restrict__ H0,            // [4096]
    float* __restrict__ cvec)          // [4096]
{
    const int j = blockIdx.x * 256 + threadIdx.x;
    const float gi = Gx[HS + j];
    const float gc = Gx[2 * HS + j];
    const float go = Gx[3 * HS + j];
    const float cn = tanhf(gc) * sigf(gi);
    cvec[j] = cn;
    H0[j] = tanhf(cn) * sigf(go);
}

// C: one wave per hidden unit j; computes 4 gate-row dots over h_prev, updates c,H[t]
__global__ __launch_bounds__(256) void steph_kernel(
    const float* __restrict__ weight,  // [16384][6144]; h-part cols [0,4096)
    const float* __restrict__ Gx,      // [4][16384]
    const float* __restrict__ Hprev,   // [4096]
    float* __restrict__ Hout,          // [4096]
    float* __restrict__ cvec,          // [4096]
    const int t)
{
    __shared__ float hs_[HS];          // 16 KB
    const int tid = threadIdx.x;
    for (int i = tid; i < HS; i += 256) hs_[i] = Hprev[i];
    __syncthreads();

    const int wave = tid >> 6, lane = tid & 63;
    const int j = blockIdx.x * 4 + wave;
    const float4* h4 = reinterpret_cast<const float4*>(hs_);

    float acc[4];
#pragma unroll
    for (int k = 0; k < 4; ++k) {
        const float4* wrow = reinterpret_cast<const float4*>(weight + (size_t)(k * HS + j) * ZD);
        float a = 0.f;
#pragma unroll
        for (int it = 0; it < (HS / 4) / 64; ++it) {   // 16 iters
            const int e = it * 64 + lane;
            const float4 w = wrow[e];
            const float4 h = h4[e];
            a += w.x * h.x + w.y * h.y + w.z * h.z + w.w * h.w;
        }
        acc[k] = a;
    }
#pragma unroll
    for (int k = 0; k < 4; ++k) acc[k] = wave_reduce(acc[k]);

    if (lane == 0) {
        const size_t gb = (size_t)t * NR;
        const float gf = acc[0] + Gx[gb + j];
        const float gi = acc[1] + Gx[gb + HS + j];
        const float gc = acc[2] + Gx[gb + 2 * HS + j];
        const float go = acc[3] + Gx[gb + 3 * HS + j];
        const float cn = cvec[j] * sigf(gf) + tanhf(gc) * sigf(gi);
        cvec[j] = cn;
        Hout[j] = tanhf(cn) * sigf(go);
    }
}

// D: logits[t][r] = b[r] + sum_i W[r][i] * H[t][i]
__global__ __launch_bounds__(256) void logits_kernel(
    const float* __restrict__ W,       // [2048][4096]
    const float* __restrict__ bvec,    // [2048]
    const float* __restrict__ H,       // [4][4096]
    float* __restrict__ logits)        // [4][2048]
{
    const int wave = threadIdx.x >> 6, lane = threadIdx.x & 63;
    const int r = blockIdx.x * 4 + wave;
    const float4* wrow = reinterpret_cast<const float4*>(W + (size_t)r * HS);
    const float4* H4 = reinterpret_cast<const float4*>(H);

    float acc[4] = {0.f, 0.f, 0.f, 0.f};
#pragma unroll
    for (int it = 0; it < (HS / 4) / 64; ++it) {   // 16 iters
        const int e = it * 64 + lane;
        const float4 w = wrow[e];
#pragma unroll
        for (int t = 0; t < 4; ++t) {
            const float4 h = H4[t * (HS / 4) + e];
            acc[t] += w.x * h.x + w.y * h.y + w.z * h.z + w.w * h.w;
        }
    }
#pragma unroll
    for (int t = 0; t < 4; ++t) acc[t] = wave_reduce(acc[t]);
    if (lane == 0) {
        const float bv = bvec[r];
#pragma unroll
        for (int t = 0; t < 4; ++t) logits[t * IS + r] = acc[t] + bv;
    }
}

// E: loss = sum_t ( logsumexp(logits[t]) - logits[t][target[t]] )
__global__ __launch_bounds__(256) void loss_kernel(
    const float* __restrict__ logits,  // [4][2048]
    const int* __restrict__ target,    // [4]
    float* __restrict__ out)
{
    __shared__ float red[256];
    const int tid = threadIdx.x;
    float total = 0.f;
    for (int t = 0; t < NT; ++t) {
        const float* row = logits + t * IS;
        float m = -1e30f;
        for (int r = tid; r < IS; r += 256) m = fmaxf(m, row[r]);
        red[tid] = m;
        __syncthreads();
        for (int s = 128; s > 0; s >>= 1) {
            if (tid < s) red[tid] = fmaxf(red[tid], red[tid + s]);
            __syncthreads();
        }
        m = red[0];
        __syncthreads();
        float sum = 0.f;
        for (int r = tid; r < IS; r += 256) sum += expf(row[r] - m);
        red[tid] = sum;
        __syncthreads();
        for (int s = 128; s > 0; s >>= 1) {
            if (tid < s) red[tid] += red[tid + s];
            __syncthreads();
        }
        if (tid == 0) {
            const float lse = m + logf(red[0]);
            total += lse - row[target[t]];
        }
        __syncthreads();
    }
    if (tid == 0) out[0] = total;
}

extern "C" void kernel_launch(void* const* d_in, const int* in_sizes, int n_in,
                              void* d_out, int out_size, void* d_ws, size_t ws_size,
                              hipStream_t stream) {
    const float* x      = (const float*)d_in[0];   // [4][1][2048]
    const int*   target = (const int*)  d_in[1];   // [4][1]
    const float* weight = (const float*)d_in[2];   // [16384][6144]
    const float* bias   = (const float*)d_in[3];   // [16384]
    const float* W      = (const float*)d_in[4];   // [2048][4096]
    const float* bvec   = (const float*)d_in[5];   // [2048]
    float* out = (float*)d_out;

    float* ws = (float*)d_ws;
    float* Gx     = ws;                                   // 4*16384 = 65536 floats
    float* H      = ws + 65536;                           // 4*4096  = 16384 floats
    float* cvec   = ws + 65536 + 16384;                   // 4096 floats
    float* logits = ws + 65536 + 16384 + 4096;            // 4*2048 = 8192 floats

    hipLaunchKernelGGL(gx_kernel, dim3(NR / 4), dim3(256), 0, stream, x, weight, bias, Gx);
    hipLaunchKernelGGL(step0_kernel, dim3(HS / 256), dim3(256), 0, stream, Gx, H, cvec);
    for (int t = 1; t < NT; ++t) {
        hipLaunchKernelGGL(steph_kernel, dim3(HS / 4), dim3(256), 0, stream,
                           weight, Gx, H + (size_t)(t - 1) * HS, H + (size_t)t * HS, cvec, t);
    }
    hipLaunchKernelGGL(logits_kernel, dim3(IS / 4), dim3(256), 0, stream, W, bvec, H, logits);
    hipLaunchKernelGGL(loss_kernel, dim3(1), dim3(256), 0, stream, logits, target, out);
}